// Round 4
// baseline (79.656 us; speedup 1.0000x reference)
//
#include <hip/hip_runtime.h>
#include <math.h>

#define BATCH 16384
#define NW 10
#define NENC 4
#define DEPTH 2

// ============================================================================
// Algebraic restructuring:
//   encoded state psi(x) has support on 16 basis states (indices a<<6),
//   psi_a = m_a * (-i)^popc(a), m_a = prod of cos/sin of the 4 encodings.
//   z_w = psi^H (U^H D_w U) psi = sum_{a,b} m_a m_b C_w[a][b],
//   C_w[a][b] = Re( i^(popc(a)-popc(b)) * sum_i sign_w(i) conj(u_a[i]) u_b[i] )
//   (real symmetric).  u_a = U e_{a<<6} is batch-independent.
// k1: 16 blocks x 1 wave propagate u_a. __shfl_xor is a DS-pipe op on CDNA;
//     1 wave/CU keeps the ~736 shuffles/wave unserialized (4 waves/CU was 4x).
// k2: 256 blocks x 1 wave compute C. Phase fold uses only Re or Im of the
//     Gram sum depending on parity of popc(a)-popc(b), so accumulate only
//     that component: 10 running sums (not 20), 60-shuffle butterfly.
// k3: one thread per batch element; C is read with block-uniform
//     compile-time offsets -> compiler emits scalar s_load (SMEM pipe),
//     no LDS, no __syncthreads, VALU-bound.
// ============================================================================

// ---- kernel 1: basis-column propagation --------------------------------
__global__ __launch_bounds__(64) void k1_basis(const float* __restrict__ theta,
                                               float2* __restrict__ u)
{
    const int lane = threadIdx.x & 63;
    const int a = blockIdx.x;            // 0..15

    float re[16], im[16];
#pragma unroll
    for (int r = 0; r < 16; ++r) { re[r] = 0.0f; im[r] = 0.0f; }
    if (lane == 0) re[a] = 1.0f;     // |a<<6>

    float ct[NW], st_[NW];
#pragma unroll
    for (int w = 0; w < NW; ++w) {
        const float h = 0.5f * theta[w];
        ct[w] = __cosf(h); st_[w] = __sinf(h);
    }

#pragma unroll 1
    for (int d = 0; d < DEPTH; ++d) {
        // RX on register wires 0..3
#pragma unroll
        for (int w = 0; w < 4; ++w) {
            const float c = ct[w], s = st_[w];
            const int m = 8 >> w;
#pragma unroll
            for (int r = 0; r < 16; ++r) {
                if (!(r & m)) {
                    const int r1 = r | m;
                    const float a0r = re[r],  a0i = im[r];
                    const float a1r = re[r1], a1i = im[r1];
                    re[r]  = c * a0r + s * a1i;
                    im[r]  = c * a0i - s * a1r;
                    re[r1] = c * a1r + s * a0i;
                    im[r1] = c * a1i - s * a0r;
                }
            }
        }
        // RX on lane wires 4..9
#pragma unroll
        for (int w = 4; w < 10; ++w) {
            const float c = ct[w], s = st_[w];
            const int lm = 32 >> (w - 4);
#pragma unroll
            for (int r = 0; r < 16; ++r) {
                const float pr = __shfl_xor(re[r], lm, 64);
                const float pi = __shfl_xor(im[r], lm, 64);
                re[r] = c * re[r] + s * pi;
                im[r] = c * im[r] - s * pr;
            }
        }
        // ring CNOTs (0,1)(1,2)(2,3): register swaps
#pragma unroll
        for (int w = 0; w < 3; ++w) {
            const int cm = 8 >> w, tm = 8 >> (w + 1);
#pragma unroll
            for (int r = 0; r < 16; ++r) {
                if ((r & cm) && !(r & tm)) {
                    const int r2 = r | tm;
                    float t;
                    t = re[r]; re[r] = re[r2]; re[r2] = t;
                    t = im[r]; im[r] = im[r2]; im[r2] = t;
                }
            }
        }
        // (3,4): odd registers swap lanes across bit5
#pragma unroll
        for (int r = 0; r < 16; ++r) {
            if (r & 1) {
                re[r] = __shfl_xor(re[r], 32, 64);
                im[r] = __shfl_xor(im[r], 32, 64);
            }
        }
        // (4,5)..(8,9): lane-bit CNOTs
#pragma unroll
        for (int w = 4; w < 9; ++w) {
            const int cm = 32 >> (w - 4), tm = 32 >> (w - 3);
            const bool ctl = (lane & cm) != 0;
#pragma unroll
            for (int r = 0; r < 16; ++r) {
                const float pr = __shfl_xor(re[r], tm, 64);
                const float pi = __shfl_xor(im[r], tm, 64);
                re[r] = ctl ? pr : re[r];
                im[r] = ctl ? pi : im[r];
            }
        }
        // (9,0): lane-bit0 controlled register-bit3 swap
        {
            const bool ctl = (lane & 1) != 0;
#pragma unroll
            for (int r = 0; r < 8; ++r) {
                const float t0r = re[r], t1r = re[r + 8];
                const float t0i = im[r], t1i = im[r + 8];
                re[r]     = ctl ? t1r : t0r;
                re[r + 8] = ctl ? t0r : t1r;
                im[r]     = ctl ? t1i : t0i;
                im[r + 8] = ctl ? t0i : t1i;
            }
        }
    }

#pragma unroll
    for (int r = 0; r < 16; ++r)
        u[a * 1024 + (r << 6) + lane] = make_float2(re[r], im[r]);
}

// ---- kernel 2: Gram matrices with Z signs, phase-folded ----------------
// One wave per (a,b) pair, q = blockIdx.x.  C layout: [q][12] floats.
// Only the Re (even popc-diff) or Im (odd) component of the Gram sum
// survives the phase fold -> accumulate exactly that one.
__global__ __launch_bounds__(64) void k2_gram(const float2* __restrict__ u,
                                              float* __restrict__ C)
{
    const int lane = threadIdx.x & 63;
    const int q = blockIdx.x;              // 0..255
    const int a = q >> 4, b = q & 15;
    const int p = (__popc(a) - __popc(b)) & 3;
    const bool useIm = (p & 1) != 0;                       // block-uniform
    const float fsign = (p == 1 || p == 2) ? -1.0f : 1.0f; // final sign

    // lane-dependent signs for wires 4..9 (mask <= 32 -> lane bits)
    float svl[6];
#pragma unroll
    for (int k = 0; k < 6; ++k)
        svl[k] = (lane & (32 >> k)) ? -1.0f : 1.0f;

    float S[NW];
#pragma unroll
    for (int w = 0; w < NW; ++w) S[w] = 0.0f;

#pragma unroll
    for (int t = 0; t < 16; ++t) {
        const int i = t * 64 + lane;
        const float2 ua = u[a * 1024 + i];
        const float2 ub = u[b * 1024 + i];
        const float v = useIm ? (ua.x * ub.y - ua.y * ub.x)   // Im(conj(ua)*ub)
                              : (ua.x * ub.x + ua.y * ub.y);  // Re(conj(ua)*ub)
        // wires 0..3: sign depends only on t (compile-time after unroll)
#pragma unroll
        for (int w = 0; w < 4; ++w) {
            const float sv = ((t * 64) & (1 << (9 - w))) ? -1.0f : 1.0f;
            S[w] = fmaf(sv, v, S[w]);
        }
        // wires 4..9: per-lane sign, hoisted
#pragma unroll
        for (int w = 4; w < NW; ++w)
            S[w] = fmaf(svl[w - 4], v, S[w]);
    }
    // wave butterfly reduction (10 values)
#pragma unroll
    for (int w = 0; w < NW; ++w) {
        float r = S[w];
#pragma unroll
        for (int ofs = 32; ofs >= 1; ofs >>= 1)
            r += __shfl_xor(r, ofs, 64);
        S[w] = r;
    }

    if (lane == 0) {
#pragma unroll
        for (int w = 0; w < NW; ++w)
            C[q * 12 + w] = fsign * S[w];
    }
}

// ---- kernel 3: per-batch quadratic forms -------------------------------
// C offsets are compile-time constants (a,b fully unrolled) -> the loads
// are block-uniform and scalarize to s_load on the SMEM pipe; the vector
// pipe only does the 1632 fma chain.  No LDS, no barrier.
__global__ __launch_bounds__(64) void k3_eval(const float* __restrict__ x,
                                              const float* __restrict__ C,
                                              float* __restrict__ out)
{
    const int bidx = blockIdx.x * 64 + threadIdx.x;   // batch element
    const float4 xv = ((const float4*)x)[bidx];

    const float c0 = __cosf(0.5f * xv.x), s0 = __sinf(0.5f * xv.x);
    const float c1 = __cosf(0.5f * xv.y), s1 = __sinf(0.5f * xv.y);
    const float c2 = __cosf(0.5f * xv.z), s2 = __sinf(0.5f * xv.z);
    const float c3 = __cosf(0.5f * xv.w), s3 = __sinf(0.5f * xv.w);

    const float t01[4] = { c0 * c1, c0 * s1, s0 * c1, s0 * s1 };
    const float t23[4] = { c2 * c3, c2 * s3, s2 * c3, s2 * s3 };
    float m[16];
#pragma unroll
    for (int r = 0; r < 16; ++r) m[r] = t01[r >> 2] * t23[r & 3];

    float z[NW];
#pragma unroll
    for (int w = 0; w < NW; ++w) z[w] = 0.0f;

#pragma unroll
    for (int a = 0; a < 16; ++a) {
#pragma unroll
        for (int b = a; b < 16; ++b) {
            const float scale = (a == b) ? 1.0f : 2.0f;   // symmetric fold
            const float p = scale * m[a] * m[b];
            const float* base = C + (a * 16 + b) * 12;    // uniform, const ofs
#pragma unroll
            for (int w = 0; w < NW; ++w)
                z[w] = fmaf(p, base[w], z[w]);
        }
    }

#pragma unroll
    for (int w = 0; w < NW; ++w) out[bidx * NW + w] = z[w];
}

extern "C" void kernel_launch(void* const* d_in, const int* in_sizes, int n_in,
                              void* d_out, int out_size, void* d_ws, size_t ws_size,
                              hipStream_t stream) {
    const float* x     = (const float*)d_in[0];
    const float* theta = (const float*)d_in[1];
    float* out = (float*)d_out;

    float2* u = (float2*)d_ws;                                 // 16*1024*8 = 131072 B
    float*  C = (float*)((char*)d_ws + 16 * 1024 * sizeof(float2)); // 256*12*4 = 12288 B

    hipLaunchKernelGGL(k1_basis, dim3(16),  dim3(64), 0, stream, theta, u);
    hipLaunchKernelGGL(k2_gram,  dim3(256), dim3(64), 0, stream, u, C);
    hipLaunchKernelGGL(k3_eval,  dim3(256), dim3(64), 0, stream, x, C, out);
}